// Round 1
// baseline (77.729 us; speedup 1.0000x reference)
//
#include <hip/hip_runtime.h>
#include <stdint.h>
#include <stddef.h>

// Problem constants (from the reference):
//   L_MAX=2, NU_MAX=3, K=8, Q=16, S=256
//   nu=2 tuples (6): (0,0),(0,1),(0,2),(1,1),(1,2),(2,2)   -> [K, Q*Q, S]  = 2048 rows each
//   nu=3 tuples (10): l1<=l2<=l3                            -> [K, Q*Q*Q,S] = 32768 rows each
//   output rows = 6*2048 + 10*32768 = 12288 + 327680 = 339968, S=256 -> 87,031,808 f32
#define KK 8
#define QQ 16
#define SS 256
#define NU2_ROWS 12288u

namespace {

// ---------- exact replication of numpy default_rng(0) ----------
struct NpPcg64 {
  unsigned __int128 state, inc;
  uint32_t uinteger;
  bool has_uint32;

  static unsigned __int128 mul128() {
    return (((unsigned __int128)2549297995355413924ULL) << 64) | 4865540595714422341ULL;
  }
  void step() { state = state * mul128() + inc; }
  uint64_t next64() {
    step();  // numpy pcg64: step THEN output (xsl-rr on new state)
    uint64_t hi = (uint64_t)(state >> 64), lo = (uint64_t)state;
    uint64_t x = hi ^ lo;
    unsigned rot = (unsigned)(state >> 122) & 63u;
    return (x >> rot) | (x << ((64u - rot) & 63u));
  }
  uint32_t next32() {
    // pcg64_next32: low half first, buffer high half
    if (has_uint32) { has_uint32 = false; return uinteger; }
    uint64_t n = next64();
    has_uint32 = true;
    uinteger = (uint32_t)(n >> 32);
    return (uint32_t)n;
  }
  double nextd() {
    return (double)(next64() >> 11) * (1.0 / 9007199254740992.0);
  }
  uint32_t lemire32(uint32_t rng) {  // rng = high-1, 1..0xFFFFFFFE
    uint32_t excl = rng + 1u;
    uint64_t m = (uint64_t)next32() * (uint64_t)excl;
    uint32_t leftover = (uint32_t)m;
    if (leftover < excl) {
      uint32_t threshold = (uint32_t)((0xFFFFFFFFu - rng) % excl);
      while (leftover < threshold) {
        m = (uint64_t)next32() * (uint64_t)excl;
        leftover = (uint32_t)m;
      }
    }
    return (uint32_t)(m >> 32);
  }
  // Generator.integers(0, high, n) with default dtype=int64:
  // random_bounded_uint64_fill -> rng==0 => all off; rng<=0xFFFFFFFF => 32-bit Lemire
  void integers(int high, int* out, int n) {
    if (high <= 1) { for (int i = 0; i < n; i++) out[i] = 0; return; }
    uint32_t rng = (uint32_t)(high - 1);
    for (int i = 0; i < n; i++) out[i] = (int)lemire32(rng);
  }
  void mults(float* out, int n) {  // (rng.random(n) + 0.5).astype(float32)
    for (int i = 0; i < n; i++) out[i] = (float)(nextd() + 0.5);
  }
};

void seed_rng0(NpPcg64& r) {
  // SeedSequence(0): entropy=[0], pool_size=4
  uint32_t pool[4];
  uint32_t hc = 0x43b0d7e5u;  // INIT_A
  auto hashmix = [&hc](uint32_t v) -> uint32_t {
    v ^= hc; hc *= 0x931e8875u; v *= hc; v ^= v >> 16; return v;
  };
  auto mix = [](uint32_t x, uint32_t y) -> uint32_t {
    uint32_t m = 0xca01f9ddu * x - 0x4973f715u * y; m ^= m >> 16; return m;
  };
  for (int i = 0; i < 4; i++) pool[i] = hashmix(0u);  // entropy word 0, then run-out
  for (int is = 0; is < 4; is++)
    for (int id = 0; id < 4; id++)
      if (is != id) pool[id] = mix(pool[id], hashmix(pool[is]));
  // generate_state(4, uint64) -> 8 uint32 words, paired little-endian
  uint32_t hb = 0x8b51f9ddu;  // INIT_B
  uint32_t w[8];
  for (int i = 0; i < 8; i++) {
    uint32_t v = pool[i & 3];
    v ^= hb; hb *= 0x58f38dedu; v *= hb; v ^= v >> 16;
    w[i] = v;
  }
  uint64_t sd[4];
  for (int i = 0; i < 4; i++) sd[i] = (uint64_t)w[2 * i] | ((uint64_t)w[2 * i + 1] << 32);
  // pcg64_set_seed: initstate = (sd0<<64)|sd1 ; initseq = (sd2<<64)|sd3
  unsigned __int128 initstate = (((unsigned __int128)sd[0]) << 64) | sd[1];
  unsigned __int128 initseq   = (((unsigned __int128)sd[2]) << 64) | sd[3];
  r.state = 0; r.inc = (initseq << 1) | 1;
  r.step(); r.state += initstate; r.step();
  r.has_uint32 = false; r.uinteger = 0;
}

struct Args {
  const float* pA2[6][KK];   // nu=2: l1-array row base (add q1*SS)
  const float* pB2[6][KK];   // nu=2: l2-array row base (add q2*SS)
  float        m2[6][KK];
  const float* pX3[10][KK];  // nu=3: parent's l1 factor row base (add q1*SS)
  const float* pY3[10][KK];  // nu=3: parent's l2 factor row base (add q2*SS)
  const float* pZ3[10][KK];  // nu=3: l3 row base (add q3*SS)
  float        m3[10][KK];
};

}  // namespace

__global__ __launch_bounds__(256) void le_kernel(Args a, float* __restrict__ out,
                                                 unsigned n4) {
  unsigned g = blockIdx.x * 256u + threadIdx.x;  // float4 index
  if (g >= n4) return;
  unsigned row = g >> 6;          // 64 float4 per row of S=256
  unsigned s4 = (g & 63u) << 2;   // element offset within row
  float4 res;
  if (row < NU2_ROWS) {
    unsigned t = row >> 11, r2 = row & 2047u;
    unsigned k = r2 >> 8, q1 = (r2 >> 4) & 15u, q2 = r2 & 15u;
    const float4 va = *(const float4*)(a.pA2[t][k] + q1 * SS + s4);
    const float4 vb = *(const float4*)(a.pB2[t][k] + q2 * SS + s4);
    float m = a.m2[t][k];
    res.x = (va.x * vb.x) * m;
    res.y = (va.y * vb.y) * m;
    res.z = (va.z * vb.z) * m;
    res.w = (va.w * vb.w) * m;
  } else {
    unsigned r = row - NU2_ROWS;
    unsigned t = r >> 15, r3 = r & 32767u;
    unsigned k = r3 >> 12, f2 = (r3 >> 4) & 255u, q3 = r3 & 15u;
    unsigned q1 = f2 >> 4, q2 = f2 & 15u;
    const float4 vx = *(const float4*)(a.pX3[t][k] + q1 * SS + s4);
    const float4 vy = *(const float4*)(a.pY3[t][k] + q2 * SS + s4);
    const float4 vz = *(const float4*)(a.pZ3[t][k] + q3 * SS + s4);
    float m = a.m3[t][k];
    // match reference rounding: parent=(x*y) stored f32, then *z, then *mult
    res.x = ((vx.x * vy.x) * vz.x) * m;
    res.y = ((vx.y * vy.y) * vz.y) * m;
    res.z = ((vx.z * vy.z) * vz.z) * m;
    res.w = ((vx.w * vy.w) * vz.w) * m;
  }
  *(float4*)(out + (size_t)g * 4u) = res;
}

extern "C" void kernel_launch(void* const* d_in, const int* in_sizes, int n_in,
                              void* d_out, int out_size, void* d_ws, size_t ws_size,
                              hipStream_t stream) {
  (void)in_sizes; (void)n_in; (void)d_ws; (void)ws_size;

  // ---- rebuild the deterministic structure (host, every call; graph-safe) ----
  NpPcg64 rng;
  seed_rng0(rng);

  static const int pairs[6][2] = {{0,0},{0,1},{0,2},{1,1},{1,2},{2,2}};
  static const int trip[10][3] = {{0,0,0},{0,0,1},{0,0,2},{0,1,1},{0,1,2},
                                  {0,2,2},{1,1,1},{1,1,2},{1,2,2},{2,2,2}};
  static const int parent[10]  = {0,0,0,1,1,2,3,3,4,5};

  int   ip2[6][KK], i12[6][KK];
  float m2v[6][KK];
  for (int t = 0; t < 6; t++) {
    rng.integers(2 * pairs[t][0] + 1, ip2[t], KK);
    rng.integers(2 * pairs[t][1] + 1, i12[t], KK);
    rng.mults(m2v[t], KK);
  }
  int   ip3[10][KK], i13[10][KK];
  float m3v[10][KK];
  for (int u = 0; u < 10; u++) {
    rng.integers(KK, ip3[u], KK);                 // high = K = 8
    rng.integers(2 * trip[u][2] + 1, i13[u], KK);
    rng.mults(m3v[u], KK);
  }

  // ---- resolve gathers to device pointers ----
  const float* base[3] = {(const float*)d_in[0], (const float*)d_in[1], (const float*)d_in[2]};
  Args a;
  for (int t = 0; t < 6; t++) {
    for (int k = 0; k < KK; k++) {
      a.pA2[t][k] = base[pairs[t][0]] + (size_t)ip2[t][k] * QQ * SS;
      a.pB2[t][k] = base[pairs[t][1]] + (size_t)i12[t][k] * QQ * SS;
      a.m2[t][k]  = m2v[t][k];
    }
  }
  for (int u = 0; u < 10; u++) {
    for (int k = 0; k < KK; k++) {
      int p = parent[u], kp = ip3[u][k];
      a.pX3[u][k] = base[pairs[p][0]] + (size_t)ip2[p][kp] * QQ * SS;
      a.pY3[u][k] = base[pairs[p][1]] + (size_t)i12[p][kp] * QQ * SS;
      a.pZ3[u][k] = base[trip[u][2]] + (size_t)i13[u][k] * QQ * SS;
      a.m3[u][k]  = m3v[u][k];
    }
  }

  unsigned n4 = (unsigned)(out_size / 4);           // 21,757,952 float4s
  unsigned blocks = (n4 + 255u) / 256u;             // 84,992
  le_kernel<<<blocks, 256, 0, stream>>>(a, (float*)d_out, n4);
}

// Round 3
// 72.400 us; speedup vs baseline: 1.0736x; 1.0736x over previous
//
#include <hip/hip_runtime.h>
#include <stdint.h>
#include <stddef.h>

// Problem constants (from the reference):
//   L_MAX=2, NU_MAX=3, K=8, Q=16, S=256
//   nu=2 tuples (6): rows [K,Q,Q]   = 2048 rows each, 6*2048  = 12288 rows
//   nu=3 tuples (10): rows [K,Q,Q,Q]= 32768 rows each, 10*32768 = 327680 rows
//   output = 339968 rows x 256 f32 = 87,031,808 f32 = 348 MB (write-bound)
#define KK 8
#define QQ 16
#define SS 256
#define NU2_ROWS 12288u

typedef float f32x4 __attribute__((ext_vector_type(4)));

namespace {

// ---------- exact replication of numpy default_rng(0) ----------
struct NpPcg64 {
  unsigned __int128 state, inc;
  uint32_t uinteger;
  bool has_uint32;

  static unsigned __int128 mul128() {
    return (((unsigned __int128)2549297995355413924ULL) << 64) | 4865540595714422341ULL;
  }
  void step() { state = state * mul128() + inc; }
  uint64_t next64() {
    step();  // numpy pcg64: step THEN output (xsl-rr on new state)
    uint64_t hi = (uint64_t)(state >> 64), lo = (uint64_t)state;
    uint64_t x = hi ^ lo;
    unsigned rot = (unsigned)(state >> 122) & 63u;
    return (x >> rot) | (x << ((64u - rot) & 63u));
  }
  uint32_t next32() {
    if (has_uint32) { has_uint32 = false; return uinteger; }
    uint64_t n = next64();
    has_uint32 = true;
    uinteger = (uint32_t)(n >> 32);
    return (uint32_t)n;
  }
  double nextd() {
    return (double)(next64() >> 11) * (1.0 / 9007199254740992.0);
  }
  uint32_t lemire32(uint32_t rng) {
    uint32_t excl = rng + 1u;
    uint64_t m = (uint64_t)next32() * (uint64_t)excl;
    uint32_t leftover = (uint32_t)m;
    if (leftover < excl) {
      uint32_t threshold = (uint32_t)((0xFFFFFFFFu - rng) % excl);
      while (leftover < threshold) {
        m = (uint64_t)next32() * (uint64_t)excl;
        leftover = (uint32_t)m;
      }
    }
    return (uint32_t)(m >> 32);
  }
  void integers(int high, int* out, int n) {
    if (high <= 1) { for (int i = 0; i < n; i++) out[i] = 0; return; }
    uint32_t rng = (uint32_t)(high - 1);
    for (int i = 0; i < n; i++) out[i] = (int)lemire32(rng);
  }
  void mults(float* out, int n) {
    for (int i = 0; i < n; i++) out[i] = (float)(nextd() + 0.5);
  }
};

void seed_rng0(NpPcg64& r) {
  uint32_t pool[4];
  uint32_t hc = 0x43b0d7e5u;  // INIT_A
  auto hashmix = [&hc](uint32_t v) -> uint32_t {
    v ^= hc; hc *= 0x931e8875u; v *= hc; v ^= v >> 16; return v;
  };
  auto mix = [](uint32_t x, uint32_t y) -> uint32_t {
    uint32_t m = 0xca01f9ddu * x - 0x4973f715u * y; m ^= m >> 16; return m;
  };
  for (int i = 0; i < 4; i++) pool[i] = hashmix(0u);
  for (int is = 0; is < 4; is++)
    for (int id = 0; id < 4; id++)
      if (is != id) pool[id] = mix(pool[id], hashmix(pool[is]));
  uint32_t hb = 0x8b51f9ddu;  // INIT_B
  uint32_t w[8];
  for (int i = 0; i < 8; i++) {
    uint32_t v = pool[i & 3];
    v ^= hb; hb *= 0x58f38dedu; v *= hb; v ^= v >> 16;
    w[i] = v;
  }
  uint64_t sd[4];
  for (int i = 0; i < 4; i++) sd[i] = (uint64_t)w[2 * i] | ((uint64_t)w[2 * i + 1] << 32);
  unsigned __int128 initstate = (((unsigned __int128)sd[0]) << 64) | sd[1];
  unsigned __int128 initseq   = (((unsigned __int128)sd[2]) << 64) | sd[3];
  r.state = 0; r.inc = (initseq << 1) | 1;
  r.step(); r.state += initstate; r.step();
  r.has_uint32 = false; r.uinteger = 0;
}

struct Args {
  const float* pA2[6][KK];   // nu=2: l1-array row base (add q1*SS)
  const float* pB2[6][KK];   // nu=2: l2-array row base (add q2*SS)
  float        m2[6][KK];
  const float* pX3[10][KK];  // nu=3: parent's l1 factor row base
  const float* pY3[10][KK];  // nu=3: parent's l2 factor row base
  const float* pZ3[10][KK];  // nu=3: l3 row base
  float        m3[10][KK];
};

}  // namespace

// One wave (64 lanes) per (tuple, k, q1[, q2]); inner loop over the last q
// index (16 iterations). Wave-invariant operands loaded once per 16 stores;
// every iteration stores one full contiguous 1 KB row slice (s4 = lane*4).
__global__ __launch_bounds__(256) void le_kernel(Args a, float* __restrict__ out,
                                                 unsigned nwaves) {
  unsigned tid = blockIdx.x * 256u + threadIdx.x;
  unsigned w = tid >> 6, lane = tid & 63u;
  if (w >= nwaves) return;
  unsigned s4 = lane << 2;

  if (w < 768u) {  // nu=2: 6*8*16 waves, loop over q2
    unsigned t = w >> 7, k = (w >> 4) & 7u, q1 = w & 15u;
    const f32x4 va = *(const f32x4*)(a.pA2[t][k] + q1 * SS + s4);
    const float* pb = a.pB2[t][k] + s4;
    float m = a.m2[t][k];
    float* po = out + (size_t)((t * 8u + k) * 16u + q1) * 16u * SS + s4;
#pragma unroll
    for (unsigned q2 = 0; q2 < 16u; ++q2) {
      f32x4 vb = *(const f32x4*)(pb + q2 * SS);
      f32x4 r = (va * vb) * m;  // reference rounding: (A*B) then *mult
      __builtin_nontemporal_store(r, (f32x4*)(po + q2 * SS));
    }
  } else {  // nu=3: 10*8*16*16 waves, loop over q3
    unsigned u = w - 768u;
    unsigned t = u >> 11, k = (u >> 8) & 7u, q1 = (u >> 4) & 15u, q2 = u & 15u;
    const f32x4 vx = *(const f32x4*)(a.pX3[t][k] + q1 * SS + s4);
    const f32x4 vy = *(const f32x4*)(a.pY3[t][k] + q2 * SS + s4);
    const float* pz = a.pZ3[t][k] + s4;
    float m = a.m3[t][k];
    f32x4 xy = vx * vy;  // parent = (x*y) rounded to f32 once (matches reference)
    float* po = out +
        (size_t)(NU2_ROWS + (((t * 8u + k) * 16u + q1) * 16u + q2) * 16u) * SS + s4;
#pragma unroll
    for (unsigned q3 = 0; q3 < 16u; ++q3) {
      f32x4 vz = *(const f32x4*)(pz + q3 * SS);
      f32x4 r = (xy * vz) * m;
      __builtin_nontemporal_store(r, (f32x4*)(po + q3 * SS));
    }
  }
}

extern "C" void kernel_launch(void* const* d_in, const int* in_sizes, int n_in,
                              void* d_out, int out_size, void* d_ws, size_t ws_size,
                              hipStream_t stream) {
  (void)in_sizes; (void)n_in; (void)d_ws; (void)ws_size; (void)out_size;

  // ---- rebuild the deterministic structure (host, every call; graph-safe) ----
  NpPcg64 rng;
  seed_rng0(rng);

  static const int pairs[6][2] = {{0,0},{0,1},{0,2},{1,1},{1,2},{2,2}};
  static const int trip[10][3] = {{0,0,0},{0,0,1},{0,0,2},{0,1,1},{0,1,2},
                                  {0,2,2},{1,1,1},{1,1,2},{1,2,2},{2,2,2}};
  static const int parent[10]  = {0,0,0,1,1,2,3,3,4,5};

  int   ip2[6][KK], i12[6][KK];
  float m2v[6][KK];
  for (int t = 0; t < 6; t++) {
    rng.integers(2 * pairs[t][0] + 1, ip2[t], KK);
    rng.integers(2 * pairs[t][1] + 1, i12[t], KK);
    rng.mults(m2v[t], KK);
  }
  int   ip3[10][KK], i13[10][KK];
  float m3v[10][KK];
  for (int u = 0; u < 10; u++) {
    rng.integers(KK, ip3[u], KK);
    rng.integers(2 * trip[u][2] + 1, i13[u], KK);
    rng.mults(m3v[u], KK);
  }

  const float* base[3] = {(const float*)d_in[0], (const float*)d_in[1], (const float*)d_in[2]};
  Args a;
  for (int t = 0; t < 6; t++) {
    for (int k = 0; k < KK; k++) {
      a.pA2[t][k] = base[pairs[t][0]] + (size_t)ip2[t][k] * QQ * SS;
      a.pB2[t][k] = base[pairs[t][1]] + (size_t)i12[t][k] * QQ * SS;
      a.m2[t][k]  = m2v[t][k];
    }
  }
  for (int u = 0; u < 10; u++) {
    for (int k = 0; k < KK; k++) {
      int p = parent[u], kp = ip3[u][k];
      a.pX3[u][k] = base[pairs[p][0]] + (size_t)ip2[p][kp] * QQ * SS;
      a.pY3[u][k] = base[pairs[p][1]] + (size_t)i12[p][kp] * QQ * SS;
      a.pZ3[u][k] = base[trip[u][2]] + (size_t)i13[u][k] * QQ * SS;
      a.m3[u][k]  = m3v[u][k];
    }
  }

  // waves: nu2 = 6*8*16 = 768; nu3 = 10*8*16*16 = 20480; total 21248
  unsigned nwaves = 21248u;
  unsigned blocks = (nwaves * 64u + 255u) / 256u;  // 5312
  le_kernel<<<blocks, 256, 0, stream>>>(a, (float*)d_out, nwaves);
}

// Round 4
// 67.333 us; speedup vs baseline: 1.1544x; 1.0752x over previous
//
#include <hip/hip_runtime.h>
#include <stdint.h>
#include <stddef.h>

// Problem constants (from the reference):
//   L_MAX=2, NU_MAX=3, K=8, Q=16, S=256
//   nu=2 tuples (6): rows [K,Q,Q]   = 2048 rows each, 6*2048  = 12288 rows
//   nu=3 tuples (10): rows [K,Q,Q,Q]= 32768 rows each, 10*32768 = 327680 rows
//   output = 339968 rows x 256 f32 = 87,031,808 f32 = 348 MB (write-bound)
#define KK 8
#define QQ 16
#define SS 256
#define NU2_ROWS 12288u

typedef float f32x4 __attribute__((ext_vector_type(4)));

namespace {

// ---------- exact replication of numpy default_rng(0) ----------
struct NpPcg64 {
  unsigned __int128 state, inc;
  uint32_t uinteger;
  bool has_uint32;

  static unsigned __int128 mul128() {
    return (((unsigned __int128)2549297995355413924ULL) << 64) | 4865540595714422341ULL;
  }
  void step() { state = state * mul128() + inc; }
  uint64_t next64() {
    step();  // numpy pcg64: step THEN output (xsl-rr on new state)
    uint64_t hi = (uint64_t)(state >> 64), lo = (uint64_t)state;
    uint64_t x = hi ^ lo;
    unsigned rot = (unsigned)(state >> 122) & 63u;
    return (x >> rot) | (x << ((64u - rot) & 63u));
  }
  uint32_t next32() {
    if (has_uint32) { has_uint32 = false; return uinteger; }
    uint64_t n = next64();
    has_uint32 = true;
    uinteger = (uint32_t)(n >> 32);
    return (uint32_t)n;
  }
  double nextd() {
    return (double)(next64() >> 11) * (1.0 / 9007199254740992.0);
  }
  uint32_t lemire32(uint32_t rng) {
    uint32_t excl = rng + 1u;
    uint64_t m = (uint64_t)next32() * (uint64_t)excl;
    uint32_t leftover = (uint32_t)m;
    if (leftover < excl) {
      uint32_t threshold = (uint32_t)((0xFFFFFFFFu - rng) % excl);
      while (leftover < threshold) {
        m = (uint64_t)next32() * (uint64_t)excl;
        leftover = (uint32_t)m;
      }
    }
    return (uint32_t)(m >> 32);
  }
  void integers(int high, int* out, int n) {
    if (high <= 1) { for (int i = 0; i < n; i++) out[i] = 0; return; }
    uint32_t rng = (uint32_t)(high - 1);
    for (int i = 0; i < n; i++) out[i] = (int)lemire32(rng);
  }
  void mults(float* out, int n) {
    for (int i = 0; i < n; i++) out[i] = (float)(nextd() + 0.5);
  }
};

void seed_rng0(NpPcg64& r) {
  uint32_t pool[4];
  uint32_t hc = 0x43b0d7e5u;  // INIT_A
  auto hashmix = [&hc](uint32_t v) -> uint32_t {
    v ^= hc; hc *= 0x931e8875u; v *= hc; v ^= v >> 16; return v;
  };
  auto mix = [](uint32_t x, uint32_t y) -> uint32_t {
    uint32_t m = 0xca01f9ddu * x - 0x4973f715u * y; m ^= m >> 16; return m;
  };
  for (int i = 0; i < 4; i++) pool[i] = hashmix(0u);
  for (int is = 0; is < 4; is++)
    for (int id = 0; id < 4; id++)
      if (is != id) pool[id] = mix(pool[id], hashmix(pool[is]));
  uint32_t hb = 0x8b51f9ddu;  // INIT_B
  uint32_t w[8];
  for (int i = 0; i < 8; i++) {
    uint32_t v = pool[i & 3];
    v ^= hb; hb *= 0x58f38dedu; v *= hb; v ^= v >> 16;
    w[i] = v;
  }
  uint64_t sd[4];
  for (int i = 0; i < 4; i++) sd[i] = (uint64_t)w[2 * i] | ((uint64_t)w[2 * i + 1] << 32);
  unsigned __int128 initstate = (((unsigned __int128)sd[0]) << 64) | sd[1];
  unsigned __int128 initseq   = (((unsigned __int128)sd[2]) << 64) | sd[3];
  r.state = 0; r.inc = (initseq << 1) | 1;
  r.step(); r.state += initstate; r.step();
  r.has_uint32 = false; r.uinteger = 0;
}

struct Args {
  const float* pA2[6][KK];   // nu=2: l1-array row base (add q1*SS)
  const float* pB2[6][KK];   // nu=2: l2-array row base (add q2*SS)
  float        m2[6][KK];
  const float* pX3[10][KK];  // nu=3: parent's l1 factor row base
  const float* pY3[10][KK];  // nu=3: parent's l2 factor row base
  const float* pZ3[10][KK];  // nu=3: l3 row base
  float        m3[10][KK];
};

}  // namespace

// One wave (64 lanes) per (tuple, k, q1[, q2]); inner loop over the last q
// index (16 iterations). Wave-invariant operands loaded once per 16 stores;
// every iteration stores one full contiguous 1 KB row slice (s4 = lane*4).
// Round-4 A/B: plain stores (L2 write-back path) instead of nontemporal.
__global__ __launch_bounds__(256) void le_kernel(Args a, float* __restrict__ out,
                                                 unsigned nwaves) {
  unsigned tid = blockIdx.x * 256u + threadIdx.x;
  unsigned w = tid >> 6, lane = tid & 63u;
  if (w >= nwaves) return;
  unsigned s4 = lane << 2;

  if (w < 768u) {  // nu=2: 6*8*16 waves, loop over q2
    unsigned t = w >> 7, k = (w >> 4) & 7u, q1 = w & 15u;
    const f32x4 va = *(const f32x4*)(a.pA2[t][k] + q1 * SS + s4);
    const float* pb = a.pB2[t][k] + s4;
    float m = a.m2[t][k];
    float* po = out + (size_t)((t * 8u + k) * 16u + q1) * 16u * SS + s4;
#pragma unroll
    for (unsigned q2 = 0; q2 < 16u; ++q2) {
      f32x4 vb = *(const f32x4*)(pb + q2 * SS);
      f32x4 r = (va * vb) * m;  // reference rounding: (A*B) then *mult
      *(f32x4*)(po + q2 * SS) = r;
    }
  } else {  // nu=3: 10*8*16*16 waves, loop over q3
    unsigned u = w - 768u;
    unsigned t = u >> 11, k = (u >> 8) & 7u, q1 = (u >> 4) & 15u, q2 = u & 15u;
    const f32x4 vx = *(const f32x4*)(a.pX3[t][k] + q1 * SS + s4);
    const f32x4 vy = *(const f32x4*)(a.pY3[t][k] + q2 * SS + s4);
    const float* pz = a.pZ3[t][k] + s4;
    float m = a.m3[t][k];
    f32x4 xy = vx * vy;  // parent = (x*y) rounded to f32 once (matches reference)
    float* po = out +
        (size_t)(NU2_ROWS + (((t * 8u + k) * 16u + q1) * 16u + q2) * 16u) * SS + s4;
#pragma unroll
    for (unsigned q3 = 0; q3 < 16u; ++q3) {
      f32x4 vz = *(const f32x4*)(pz + q3 * SS);
      f32x4 r = (xy * vz) * m;
      *(f32x4*)(po + q3 * SS) = r;
    }
  }
}

extern "C" void kernel_launch(void* const* d_in, const int* in_sizes, int n_in,
                              void* d_out, int out_size, void* d_ws, size_t ws_size,
                              hipStream_t stream) {
  (void)in_sizes; (void)n_in; (void)d_ws; (void)ws_size; (void)out_size;

  // ---- rebuild the deterministic structure (host, every call; graph-safe) ----
  NpPcg64 rng;
  seed_rng0(rng);

  static const int pairs[6][2] = {{0,0},{0,1},{0,2},{1,1},{1,2},{2,2}};
  static const int trip[10][3] = {{0,0,0},{0,0,1},{0,0,2},{0,1,1},{0,1,2},
                                  {0,2,2},{1,1,1},{1,1,2},{1,2,2},{2,2,2}};
  static const int parent[10]  = {0,0,0,1,1,2,3,3,4,5};

  int   ip2[6][KK], i12[6][KK];
  float m2v[6][KK];
  for (int t = 0; t < 6; t++) {
    rng.integers(2 * pairs[t][0] + 1, ip2[t], KK);
    rng.integers(2 * pairs[t][1] + 1, i12[t], KK);
    rng.mults(m2v[t], KK);
  }
  int   ip3[10][KK], i13[10][KK];
  float m3v[10][KK];
  for (int u = 0; u < 10; u++) {
    rng.integers(KK, ip3[u], KK);
    rng.integers(2 * trip[u][2] + 1, i13[u], KK);
    rng.mults(m3v[u], KK);
  }

  const float* base[3] = {(const float*)d_in[0], (const float*)d_in[1], (const float*)d_in[2]};
  Args a;
  for (int t = 0; t < 6; t++) {
    for (int k = 0; k < KK; k++) {
      a.pA2[t][k] = base[pairs[t][0]] + (size_t)ip2[t][k] * QQ * SS;
      a.pB2[t][k] = base[pairs[t][1]] + (size_t)i12[t][k] * QQ * SS;
      a.m2[t][k]  = m2v[t][k];
    }
  }
  for (int u = 0; u < 10; u++) {
    for (int k = 0; k < KK; k++) {
      int p = parent[u], kp = ip3[u][k];
      a.pX3[u][k] = base[pairs[p][0]] + (size_t)ip2[p][kp] * QQ * SS;
      a.pY3[u][k] = base[pairs[p][1]] + (size_t)i12[p][kp] * QQ * SS;
      a.pZ3[u][k] = base[trip[u][2]] + (size_t)i13[u][k] * QQ * SS;
      a.m3[u][k]  = m3v[u][k];
    }
  }

  // waves: nu2 = 6*8*16 = 768; nu3 = 10*8*16*16 = 20480; total 21248
  unsigned nwaves = 21248u;
  unsigned blocks = (nwaves * 64u + 255u) / 256u;  // 5312
  le_kernel<<<blocks, 256, 0, stream>>>(a, (float*)d_out, nwaves);
}

// Round 5
// 66.911 us; speedup vs baseline: 1.1617x; 1.0063x over previous
//
#include <hip/hip_runtime.h>
#include <stdint.h>
#include <stddef.h>

// Problem constants (from the reference):
//   L_MAX=2, NU_MAX=3, K=8, Q=16, S=256
//   nu=2 tuples (6): rows [K,Q,Q]   = 2048 rows each, 6*2048  = 12288 rows
//   nu=3 tuples (10): rows [K,Q,Q,Q]= 32768 rows each, 10*32768 = 327680 rows
//   output = 339968 rows x 256 f32 = 87,031,808 f32 = 348 MB (write-bound)
#define KK 8
#define QQ 16
#define SS 256
#define NU2_ROWS 12288u
#define NUNITS 21248u   // nu2: 6*8*16 = 768 ; nu3: 10*8*16*16 = 20480
#define NWAVES 2048u    // persistent waves (512 blocks x 256 threads)

typedef float f32x4 __attribute__((ext_vector_type(4)));

namespace {

// ---------- exact replication of numpy default_rng(0) ----------
struct NpPcg64 {
  unsigned __int128 state, inc;
  uint32_t uinteger;
  bool has_uint32;

  static unsigned __int128 mul128() {
    return (((unsigned __int128)2549297995355413924ULL) << 64) | 4865540595714422341ULL;
  }
  void step() { state = state * mul128() + inc; }
  uint64_t next64() {
    step();  // numpy pcg64: step THEN output (xsl-rr on new state)
    uint64_t hi = (uint64_t)(state >> 64), lo = (uint64_t)state;
    uint64_t x = hi ^ lo;
    unsigned rot = (unsigned)(state >> 122) & 63u;
    return (x >> rot) | (x << ((64u - rot) & 63u));
  }
  uint32_t next32() {
    if (has_uint32) { has_uint32 = false; return uinteger; }
    uint64_t n = next64();
    has_uint32 = true;
    uinteger = (uint32_t)(n >> 32);
    return (uint32_t)n;
  }
  double nextd() {
    return (double)(next64() >> 11) * (1.0 / 9007199254740992.0);
  }
  uint32_t lemire32(uint32_t rng) {
    uint32_t excl = rng + 1u;
    uint64_t m = (uint64_t)next32() * (uint64_t)excl;
    uint32_t leftover = (uint32_t)m;
    if (leftover < excl) {
      uint32_t threshold = (uint32_t)((0xFFFFFFFFu - rng) % excl);
      while (leftover < threshold) {
        m = (uint64_t)next32() * (uint64_t)excl;
        leftover = (uint32_t)m;
      }
    }
    return (uint32_t)(m >> 32);
  }
  void integers(int high, int* out, int n) {
    if (high <= 1) { for (int i = 0; i < n; i++) out[i] = 0; return; }
    uint32_t rng = (uint32_t)(high - 1);
    for (int i = 0; i < n; i++) out[i] = (int)lemire32(rng);
  }
  void mults(float* out, int n) {
    for (int i = 0; i < n; i++) out[i] = (float)(nextd() + 0.5);
  }
};

void seed_rng0(NpPcg64& r) {
  uint32_t pool[4];
  uint32_t hc = 0x43b0d7e5u;  // INIT_A
  auto hashmix = [&hc](uint32_t v) -> uint32_t {
    v ^= hc; hc *= 0x931e8875u; v *= hc; v ^= v >> 16; return v;
  };
  auto mix = [](uint32_t x, uint32_t y) -> uint32_t {
    uint32_t m = 0xca01f9ddu * x - 0x4973f715u * y; m ^= m >> 16; return m;
  };
  for (int i = 0; i < 4; i++) pool[i] = hashmix(0u);
  for (int is = 0; is < 4; is++)
    for (int id = 0; id < 4; id++)
      if (is != id) pool[id] = mix(pool[id], hashmix(pool[is]));
  uint32_t hb = 0x8b51f9ddu;  // INIT_B
  uint32_t w[8];
  for (int i = 0; i < 8; i++) {
    uint32_t v = pool[i & 3];
    v ^= hb; hb *= 0x58f38dedu; v *= hb; v ^= v >> 16;
    w[i] = v;
  }
  uint64_t sd[4];
  for (int i = 0; i < 4; i++) sd[i] = (uint64_t)w[2 * i] | ((uint64_t)w[2 * i + 1] << 32);
  unsigned __int128 initstate = (((unsigned __int128)sd[0]) << 64) | sd[1];
  unsigned __int128 initseq   = (((unsigned __int128)sd[2]) << 64) | sd[3];
  r.state = 0; r.inc = (initseq << 1) | 1;
  r.step(); r.state += initstate; r.step();
  r.has_uint32 = false; r.uinteger = 0;
}

struct Args {
  const float* pA2[6][KK];   // nu=2: l1-array row base (add q1*SS)
  const float* pB2[6][KK];   // nu=2: l2-array row base (add q2*SS)
  float        m2[6][KK];
  const float* pX3[10][KK];  // nu=3: parent's l1 factor row base
  const float* pY3[10][KK];  // nu=3: parent's l2 factor row base
  const float* pZ3[10][KK];  // nu=3: l3 row base
  float        m3[10][KK];
};

}  // namespace

// Persistent waves: NWAVES waves grid-stride over NUNITS work units.
// Each unit = one (tuple, k, q1[, q2]); inner loop over last q (16 x 1 KB
// coalesced row stores). Wave-invariant operands loaded once per 16 stores;
// store-drain amortized over ~10 units per wave.
__global__ __launch_bounds__(256) void le_kernel(Args a, float* __restrict__ out) {
  unsigned gwave = (blockIdx.x * 256u + threadIdx.x) >> 6;
  unsigned s4 = (threadIdx.x & 63u) << 2;

  for (unsigned w = gwave; w < NUNITS; w += NWAVES) {
    if (w < 768u) {  // nu=2: loop over q2
      unsigned t = w >> 7, k = (w >> 4) & 7u, q1 = w & 15u;
      const f32x4 va = *(const f32x4*)(a.pA2[t][k] + q1 * SS + s4);
      const float* pb = a.pB2[t][k] + s4;
      float m = a.m2[t][k];
      float* po = out + (size_t)((t * 8u + k) * 16u + q1) * 16u * SS + s4;
#pragma unroll
      for (unsigned q2 = 0; q2 < 16u; ++q2) {
        f32x4 vb = *(const f32x4*)(pb + q2 * SS);
        f32x4 r = (va * vb) * m;  // reference rounding: (A*B) then *mult
        *(f32x4*)(po + q2 * SS) = r;
      }
    } else {  // nu=3: loop over q3
      unsigned u = w - 768u;
      unsigned t = u >> 11, k = (u >> 8) & 7u, q1 = (u >> 4) & 15u, q2 = u & 15u;
      const f32x4 vx = *(const f32x4*)(a.pX3[t][k] + q1 * SS + s4);
      const f32x4 vy = *(const f32x4*)(a.pY3[t][k] + q2 * SS + s4);
      const float* pz = a.pZ3[t][k] + s4;
      float m = a.m3[t][k];
      f32x4 xy = vx * vy;  // parent = (x*y) rounded to f32 once (matches reference)
      float* po = out +
          (size_t)(NU2_ROWS + (((t * 8u + k) * 16u + q1) * 16u + q2) * 16u) * SS + s4;
#pragma unroll
      for (unsigned q3 = 0; q3 < 16u; ++q3) {
        f32x4 vz = *(const f32x4*)(pz + q3 * SS);
        f32x4 r = (xy * vz) * m;
        *(f32x4*)(po + q3 * SS) = r;
      }
    }
  }
}

extern "C" void kernel_launch(void* const* d_in, const int* in_sizes, int n_in,
                              void* d_out, int out_size, void* d_ws, size_t ws_size,
                              hipStream_t stream) {
  (void)in_sizes; (void)n_in; (void)d_ws; (void)ws_size; (void)out_size;

  // ---- rebuild the deterministic structure (host, every call; graph-safe) ----
  NpPcg64 rng;
  seed_rng0(rng);

  static const int pairs[6][2] = {{0,0},{0,1},{0,2},{1,1},{1,2},{2,2}};
  static const int trip[10][3] = {{0,0,0},{0,0,1},{0,0,2},{0,1,1},{0,1,2},
                                  {0,2,2},{1,1,1},{1,1,2},{1,2,2},{2,2,2}};
  static const int parent[10]  = {0,0,0,1,1,2,3,3,4,5};

  int   ip2[6][KK], i12[6][KK];
  float m2v[6][KK];
  for (int t = 0; t < 6; t++) {
    rng.integers(2 * pairs[t][0] + 1, ip2[t], KK);
    rng.integers(2 * pairs[t][1] + 1, i12[t], KK);
    rng.mults(m2v[t], KK);
  }
  int   ip3[10][KK], i13[10][KK];
  float m3v[10][KK];
  for (int u = 0; u < 10; u++) {
    rng.integers(KK, ip3[u], KK);
    rng.integers(2 * trip[u][2] + 1, i13[u], KK);
    rng.mults(m3v[u], KK);
  }

  const float* base[3] = {(const float*)d_in[0], (const float*)d_in[1], (const float*)d_in[2]};
  Args a;
  for (int t = 0; t < 6; t++) {
    for (int k = 0; k < KK; k++) {
      a.pA2[t][k] = base[pairs[t][0]] + (size_t)ip2[t][k] * QQ * SS;
      a.pB2[t][k] = base[pairs[t][1]] + (size_t)i12[t][k] * QQ * SS;
      a.m2[t][k]  = m2v[t][k];
    }
  }
  for (int u = 0; u < 10; u++) {
    for (int k = 0; k < KK; k++) {
      int p = parent[u], kp = ip3[u][k];
      a.pX3[u][k] = base[pairs[p][0]] + (size_t)ip2[p][kp] * QQ * SS;
      a.pY3[u][k] = base[pairs[p][1]] + (size_t)i12[p][kp] * QQ * SS;
      a.pZ3[u][k] = base[trip[u][2]] + (size_t)i13[u][k] * QQ * SS;
      a.m3[u][k]  = m3v[u][k];
    }
  }

  unsigned blocks = NWAVES * 64u / 256u;  // 512 blocks = 2048 waves
  le_kernel<<<blocks, 256, 0, stream>>>(a, (float*)d_out);
}